// Round 4
// baseline (61.573 us; speedup 1.0000x reference)
//
#include <hip/hip_runtime.h>
#include <math.h>

// Problem constants (fixed by the reference)
#define B_   16
#define F_   32
#define NP_  128   // Np = FNP / F = 4096/32
#define D_   512
#define P_   16
#define KC   64            // K-chunk in floats (256 B per row per chunk)
#define NCH  (D_ / KC)     // 8 chunks

// 1024 threads = 16 waves/block; 2 blocks/CU (grid=512 on 256 CUs) -> 32 waves/CU.
// launch_bounds(1024, 8): 8 waves/SIMD resident -> VGPR capped at 64.
__global__ __launch_bounds__(1024, 8)
void pd_kernel(const float* __restrict__ ts,
               const float* __restrict__ W,
               const float* __restrict__ bias,
               float* __restrict__ out, int T)
{
    // staging: 2 buffers x 128 rows x 64 floats = 64 KB; reused as raw_lds later
    __shared__ float smem[2 * NP_ * KC];

    const int tid  = threadIdx.x;
    const int lane = tid & 63;
    const int wave = tid >> 6;                       // 0..15
    // wave -> (row half, e-group): row = (wave&1)*64+lane, e's 4*(wave>>1)..+3
    const int n    = ((wave & 1) << 6) + lane;       // this thread's row 0..127
    const int e0   = __builtin_amdgcn_readfirstlane((wave >> 1) << 2);

    // XCD-aware block-id encoding: d = (b&7) + 8*(f + 32*(b>>3))
    // => all 32 f's of one b land on the same XCD so strided output stores
    //    merge in that XCD's L2 (WRITE_SIZE measured at ideal 4.1 MB).
    const int d = blockIdx.x;
    const int b = (d & 7) | ((d >> 8) << 3);
    const int f = (d >> 3) & 31;
    const float* __restrict__ tsb = ts + ((size_t)b * F_ + f) * NP_ * D_;

    float acc[4];
#pragma unroll
    for (int eo = 0; eo < 4; ++eo) acc[eo] = 0.f;

    // ---- stage chunk 0 into buffer 0 (pre-swizzled global source, linear LDS dest)
#pragma unroll
    for (int it = 0; it < 2; ++it) {
        int slot = it * 1024 + tid;          // 0..2047 16B-slots (128 rows x 16 quads)
        int rr = slot >> 4;
        int ql = slot & 15;
        int qg = ql ^ (rr & 7);              // XOR quad swizzle (bijective per row)
        const float* src = tsb + rr * D_ + (qg << 2);
        __builtin_amdgcn_global_load_lds(
            (const __attribute__((address_space(1))) unsigned int*)src,
            (__attribute__((address_space(3))) unsigned int*)&smem[slot << 2],
            16, 0, 0);
    }
    __syncthreads();

    const int sw = n & 7;

    for (int c = 0; c < NCH; ++c) {
        // ---- stage chunk c+1 into the other buffer (overlaps with compute below)
        if (c + 1 < NCH) {
            const int k0 = (c + 1) * KC;
            float* dstb = smem + ((c + 1) & 1) * (NP_ * KC);
#pragma unroll
            for (int it = 0; it < 2; ++it) {
                int slot = it * 1024 + tid;
                int rr = slot >> 4;
                int ql = slot & 15;
                int qg = ql ^ (rr & 7);
                const float* src = tsb + rr * D_ + k0 + (qg << 2);
                __builtin_amdgcn_global_load_lds(
                    (const __attribute__((address_space(1))) unsigned int*)src,
                    (__attribute__((address_space(3))) unsigned int*)&dstb[slot << 2],
                    16, 0, 0);
            }
        }

        // ---- compute on current buffer: this thread's single row, 4 e's,
        //      interleaved q-loop (round-2 structure: compiler pipelines
        //      ds_read / s_load / FMA with counted waits)
        const float* row = smem + (c & 1) * (NP_ * KC) + n * KC;
        const int kb = c * KC;
#pragma unroll
        for (int q = 0; q < 16; ++q) {
            // swizzled read: global quad q lives at LDS quad q^(row&7)
            const float4 a = *(const float4*)(row + ((q ^ sw) << 2));
            const float* wq = W + kb + (q << 2);   // wave-uniform -> s_load
#pragma unroll
            for (int eo = 0; eo < 4; ++eo) {
                const float* we = wq + (e0 + eo) * D_;
                acc[eo] += a.x * we[0] + a.y * we[1] + a.z * we[2] + a.w * we[3];
            }
        }
        __syncthreads();   // drains stage(c+1) (vmcnt) + all ds_reads of buf (lgkm)
    }

    // ---- epilogue: raw -> LDS (padded stride 33, conflict-free), then gather
#pragma unroll
    for (int eo = 0; eo < 4; ++eo) {
        const int e = e0 + eo;
        float v = acc[eo] + bias[e];
        if (e >= P_) v = fmaxf(expf(v), 1e-6f);   // sigma half (wave-uniform branch)
        smem[n * 33 + e] = v;
    }
    __syncthreads();

    // out[b, t, f] = sum_{n: p=t-8n in [0,16)} raw[n][p (+16)] / count(t)
    const int TF = T * F_;
    const size_t halfoff = (size_t)B_ * TF;
    for (int item = tid; item < 2 * T; item += 1024) {
        const int half = (item >= T) ? 1 : 0;
        const int t    = item - half * T;
        const int nmax = min(NP_ - 1, t >> 3);
        const int nmin = (t > 8) ? ((t - 8) >> 3) : 0;
        float sum = 0.f;
        const int cnt = nmax - nmin + 1;
        for (int nn = nmin; nn <= nmax; ++nn)
            sum += smem[nn * 33 + (half << 4) + (t - (nn << 3))];
        const float r = (cnt > 0) ? sum / (float)cnt : 0.f;
        out[(size_t)half * halfoff + (size_t)b * TF + (size_t)t * F_ + f] = r;
    }
}

extern "C" void kernel_launch(void* const* d_in, const int* in_sizes, int n_in,
                              void* d_out, int out_size, void* d_ws, size_t ws_size,
                              hipStream_t stream)
{
    const float* ts   = (const float*)d_in[0];
    const float* W    = (const float*)d_in[1];
    const float* bias = (const float*)d_in[2];
    float* out = (float*)d_out;

    // T derived on host from out_size = 2 * B * T * F
    const int T = out_size / (2 * B_ * F_);

    dim3 grid(B_ * F_);   // 512 blocks, one per (b, f), XCD-encoded id
    dim3 block(1024);
    pd_kernel<<<grid, block, 0, stream>>>(ts, W, bias, out, T);
}

// Round 5
// 60.888 us; speedup vs baseline: 1.0112x; 1.0112x over previous
//
#include <hip/hip_runtime.h>
#include <math.h>

// Problem constants (fixed by the reference)
#define B_   16
#define F_   32
#define NP_  128   // Np = FNP / F = 4096/32
#define D_   512
#define P_   16
#define KC   64            // K-chunk in floats (256 B per row per chunk)
#define NCH  (D_ / KC)     // 8 chunks

// 512 threads = 8 waves; grid 512 on 256 CUs -> 2 blocks/CU, 16 waves/CU.
// (512,4): VGPR cap 128 -> room for deep ds_read prefetch.
__global__ __launch_bounds__(512, 4)
void pd_kernel(const float* __restrict__ ts,
               const float* __restrict__ W,
               const float* __restrict__ bias,
               float* __restrict__ out, int T)
{
    // staging: 2 buffers x 128 rows x 64 floats = 64 KB; reused as raw_lds later
    __shared__ float smem[2 * NP_ * KC];

    const int tid  = threadIdx.x;
    const int lane = tid & 63;
    const int wave = tid >> 6;                        // 0..7
    // wave -> (row half, e-octet): row = (wave&1)*64+lane, e's 8*(wave>>1)..+7
    const int n    = ((wave & 1) << 6) + lane;        // this thread's row 0..127
    const int e0   = __builtin_amdgcn_readfirstlane((wave >> 1) << 3); // 0,8,16,24

    // XCD-aware block-id encoding: d = (b&7) + 8*(f + 32*(b>>3))
    // => all 32 f's of one b land on the same XCD so strided output stores
    //    merge in that XCD's L2 (WRITE_SIZE measured at ideal 4.1 MB).
    const int d = blockIdx.x;
    const int b = (d & 7) | ((d >> 8) << 3);
    const int f = (d >> 3) & 31;
    const float* __restrict__ tsb = ts + ((size_t)b * F_ + f) * NP_ * D_;

    float acc[8];
#pragma unroll
    for (int eo = 0; eo < 8; ++eo) acc[eo] = 0.f;

    // ---- stage chunk 0 into buffer 0.
    // Swizzle: global quad qg = ql ^ (row & 15)  (16 quads per row at KC=64).
    // Bijective per row; read side uses the same involution -> within every
    // 16-lane quarter-wave the 16 rows hit 16 DISTINCT 16B columns (balanced
    // over all 32 banks), eliminating the measured 2x bank-conflict tax.
#pragma unroll
    for (int it = 0; it < 4; ++it) {
        int slot = it * 512 + tid;           // 0..2047 16B-slots (128 rows x 16 quads)
        int rr = slot >> 4;
        int ql = slot & 15;
        int qg = ql ^ (rr & 15);
        const float* src = tsb + rr * D_ + (qg << 2);
        __builtin_amdgcn_global_load_lds(
            (const __attribute__((address_space(1))) unsigned int*)src,
            (__attribute__((address_space(3))) unsigned int*)&smem[slot << 2],
            16, 0, 0);
    }
    __syncthreads();

    const int sw = n & 15;

    for (int c = 0; c < NCH; ++c) {
        // ---- stage chunk c+1 into the other buffer (overlaps with compute below)
        if (c + 1 < NCH) {
            const int k0 = (c + 1) * KC;
            float* dstb = smem + ((c + 1) & 1) * (NP_ * KC);
#pragma unroll
            for (int it = 0; it < 4; ++it) {
                int slot = it * 512 + tid;
                int rr = slot >> 4;
                int ql = slot & 15;
                int qg = ql ^ (rr & 15);
                const float* src = tsb + rr * D_ + k0 + (qg << 2);
                __builtin_amdgcn_global_load_lds(
                    (const __attribute__((address_space(1))) unsigned int*)src,
                    (__attribute__((address_space(3))) unsigned int*)&dstb[slot << 2],
                    16, 0, 0);
            }
        }

        // ---- compute on current buffer: this thread's single row, 8 e's,
        //      interleaved q-loop; acc[8] gives 8 independent FMA chains and
        //      the unrolled q-loop lets the compiler run ds_reads ahead.
        const float* row = smem + (c & 1) * (NP_ * KC) + n * KC;
        const int kb = c * KC;
#pragma unroll
        for (int q = 0; q < 16; ++q) {
            const float4 a = *(const float4*)(row + ((q ^ sw) << 2));
            const float* wq = W + kb + (q << 2);   // wave-uniform -> s_load
#pragma unroll
            for (int eo = 0; eo < 8; ++eo) {
                const float* we = wq + (e0 + eo) * D_;
                acc[eo] += a.x * we[0] + a.y * we[1] + a.z * we[2] + a.w * we[3];
            }
        }
        __syncthreads();   // drains stage(c+1) (vmcnt) + all ds_reads of buf (lgkm)
    }

    // ---- epilogue: raw -> LDS (padded stride 33, conflict-free), then gather
#pragma unroll
    for (int eo = 0; eo < 8; ++eo) {
        const int e = e0 + eo;
        float v = acc[eo] + bias[e];
        if (e >= P_) v = fmaxf(expf(v), 1e-6f);   // sigma half (wave-uniform branch)
        smem[n * 33 + e] = v;
    }
    __syncthreads();

    // out[b, t, f] = sum_{n: p=t-8n in [0,16)} raw[n][p (+16)] / count(t)
    const int TF = T * F_;
    const size_t halfoff = (size_t)B_ * TF;
    for (int item = tid; item < 2 * T; item += 512) {
        const int half = (item >= T) ? 1 : 0;
        const int t    = item - half * T;
        const int nmax = min(NP_ - 1, t >> 3);
        const int nmin = (t > 8) ? ((t - 8) >> 3) : 0;
        float sum = 0.f;
        const int cnt = nmax - nmin + 1;
        for (int nn = nmin; nn <= nmax; ++nn)
            sum += smem[nn * 33 + (half << 4) + (t - (nn << 3))];
        const float r = (cnt > 0) ? sum / (float)cnt : 0.f;
        out[(size_t)half * halfoff + (size_t)b * TF + (size_t)t * F_ + f] = r;
    }
}

extern "C" void kernel_launch(void* const* d_in, const int* in_sizes, int n_in,
                              void* d_out, int out_size, void* d_ws, size_t ws_size,
                              hipStream_t stream)
{
    const float* ts   = (const float*)d_in[0];
    const float* W    = (const float*)d_in[1];
    const float* bias = (const float*)d_in[2];
    float* out = (float*)d_out;

    // T derived on host from out_size = 2 * B * T * F
    const int T = out_size / (2 * B_ * F_);

    dim3 grid(B_ * F_);   // 512 blocks, one per (b, f), XCD-encoded id
    dim3 block(512);
    pd_kernel<<<grid, block, 0, stream>>>(ts, W, bias, out, T);
}

// Round 6
// 49.743 us; speedup vs baseline: 1.2378x; 1.2241x over previous
//
#include <hip/hip_runtime.h>
#include <math.h>

// Problem constants (fixed by the reference)
#define B_   16
#define F_   32
#define NP_  128   // Np = FNP / F = 4096/32
#define D_   512
#define P_   16
#define KC   64            // K-chunk in floats (256 B per row per chunk)
#define NCH  (D_ / KC)     // 8 chunks

// 512 threads = 8 waves; grid 512 on 256 CUs -> 2 blocks/CU, 16 waves/CU.
// Shape: R2's best (2 rows x 4 e per thread), wave w owns e's 4w..4w+3.
__global__ __launch_bounds__(512, 4)
void pd_kernel(const float* __restrict__ ts,
               const float* __restrict__ W,
               const float* __restrict__ bias,
               float* __restrict__ out, int T)
{
    // staging: 2 buffers x 128 rows x 64 floats = 64 KB; reused as raw_lds later
    __shared__ float smem[2 * NP_ * KC];

    const int tid  = threadIdx.x;
    const int lane = tid & 63;
    // wave w -> e's 4w..4w+3 (wave-uniform; forces s_load for W)
    const int e0   = __builtin_amdgcn_readfirstlane((tid >> 6) << 2);

    // XCD-aware block-id encoding: d = (b&7) + 8*(f + 32*(b>>3))
    // => all 32 f's of one b land on the same XCD so strided output stores
    //    merge in that XCD's L2 (WRITE_SIZE measured at ideal 4.1 MB).
    const int d = blockIdx.x;
    const int b = (d & 7) | ((d >> 8) << 3);
    const int f = (d >> 3) & 31;
    const float* __restrict__ tsb = ts + ((size_t)b * F_ + f) * NP_ * D_;

    float acc[2][4];
#pragma unroll
    for (int j = 0; j < 2; ++j)
#pragma unroll
        for (int eo = 0; eo < 4; ++eo) acc[j][eo] = 0.f;

    // ---- stage chunk 0 into buffer 0.
    // Swizzle qg = ql ^ (row & 15): bijective per row; within every 16-lane
    // quarter-wave the 16 rows hit 16 DISTINCT 16B columns -> conflict-free
    // (measured R5: bank-conflict cycles 4.39M -> 194K).
#pragma unroll
    for (int it = 0; it < 4; ++it) {
        int slot = it * 512 + tid;           // 0..2047 16B-slots (128 rows x 16 quads)
        int rr = slot >> 4;
        int ql = slot & 15;
        int qg = ql ^ (rr & 15);
        const float* src = tsb + rr * D_ + (qg << 2);
        __builtin_amdgcn_global_load_lds(
            (const __attribute__((address_space(1))) unsigned int*)src,
            (__attribute__((address_space(3))) unsigned int*)&smem[slot << 2],
            16, 0, 0);
    }
    __syncthreads();

    const int sw = lane & 15;   // rows lane and lane+64 share (lane & 15)

    for (int c = 0; c < NCH; ++c) {
        // ---- stage chunk c+1 into the other buffer (overlaps with compute below)
        if (c + 1 < NCH) {
            const int k0 = (c + 1) * KC;
            float* dstb = smem + ((c + 1) & 1) * (NP_ * KC);
#pragma unroll
            for (int it = 0; it < 4; ++it) {
                int slot = it * 512 + tid;
                int rr = slot >> 4;
                int ql = slot & 15;
                int qg = ql ^ (rr & 15);
                const float* src = tsb + rr * D_ + k0 + (qg << 2);
                __builtin_amdgcn_global_load_lds(
                    (const __attribute__((address_space(1))) unsigned int*)src,
                    (__attribute__((address_space(3))) unsigned int*)&dstb[slot << 2],
                    16, 0, 0);
            }
        }

        // ---- compute on current buffer: 2 rows (lane, lane+64) x 4 e's.
        // Quarter-chunk structure: hoist W into SGPRs as 4 merged
        // s_load_dwordx16 per quarter, then 4 pure DS+FMA q-steps.
        // This removes the per-q s_load/ds_read lgkmcnt coupling that was
        // forcing full drains (R3/R5 post-mortem).
        const float* row0 = smem + (c & 1) * (NP_ * KC) + lane * KC;
        const float* row1 = row0 + 64 * KC;
        const int kb = c * KC;
#pragma unroll
        for (int u = 0; u < 4; ++u) {
            // 4 x 16 consecutive wave-uniform floats -> SGPRs
            float wv[4][16];
#pragma unroll
            for (int eo = 0; eo < 4; ++eo) {
                const float* we = W + __builtin_amdgcn_readfirstlane(
                                        (e0 + eo) * D_ + kb + u * 16);
#pragma unroll
                for (int jj = 0; jj < 16; ++jj) wv[eo][jj] = we[jj];
            }
#pragma unroll
            for (int kq = 0; kq < 4; ++kq) {
                const int q = (u << 2) + kq;
                const int off = ((q ^ sw) << 2);
                const float4 a0 = *(const float4*)(row0 + off);
                const float4 a1 = *(const float4*)(row1 + off);
#pragma unroll
                for (int eo = 0; eo < 4; ++eo) {
                    const float w0 = wv[eo][kq * 4 + 0];
                    const float w1 = wv[eo][kq * 4 + 1];
                    const float w2 = wv[eo][kq * 4 + 2];
                    const float w3 = wv[eo][kq * 4 + 3];
                    acc[0][eo] += a0.x * w0 + a0.y * w1 + a0.z * w2 + a0.w * w3;
                    acc[1][eo] += a1.x * w0 + a1.y * w1 + a1.z * w2 + a1.w * w3;
                }
            }
        }
        __syncthreads();   // drains stage(c+1) (vmcnt) + all ds_reads of buf (lgkm)
    }

    // ---- epilogue: raw -> LDS (padded stride 33, conflict-free), then gather
#pragma unroll
    for (int j = 0; j < 2; ++j) {
        const int n = lane + (j << 6);
#pragma unroll
        for (int eo = 0; eo < 4; ++eo) {
            const int e = e0 + eo;
            float v = acc[j][eo] + bias[e];
            if (e >= P_) v = fmaxf(expf(v), 1e-6f);   // sigma half (wave-uniform branch)
            smem[n * 33 + e] = v;
        }
    }
    __syncthreads();

    // out[b, t, f] = sum_{n: p=t-8n in [0,16)} raw[n][p (+16)] / count(t)
    const int TF = T * F_;
    const size_t halfoff = (size_t)B_ * TF;
    for (int item = tid; item < 2 * T; item += 512) {
        const int half = (item >= T) ? 1 : 0;
        const int t    = item - half * T;
        const int nmax = min(NP_ - 1, t >> 3);
        const int nmin = (t > 8) ? ((t - 8) >> 3) : 0;
        float sum = 0.f;
        const int cnt = nmax - nmin + 1;
        for (int nn = nmin; nn <= nmax; ++nn)
            sum += smem[nn * 33 + (half << 4) + (t - (nn << 3))];
        const float r = (cnt > 0) ? sum / (float)cnt : 0.f;
        out[(size_t)half * halfoff + (size_t)b * TF + (size_t)t * F_ + f] = r;
    }
}

extern "C" void kernel_launch(void* const* d_in, const int* in_sizes, int n_in,
                              void* d_out, int out_size, void* d_ws, size_t ws_size,
                              hipStream_t stream)
{
    const float* ts   = (const float*)d_in[0];
    const float* W    = (const float*)d_in[1];
    const float* bias = (const float*)d_in[2];
    float* out = (float*)d_out;

    // T derived on host from out_size = 2 * B * T * F
    const int T = out_size / (2 * B_ * F_);

    dim3 grid(B_ * F_);   // 512 blocks, one per (b, f), XCD-encoded id
    dim3 block(512);
    pd_kernel<<<grid, block, 0, stream>>>(ts, W, bias, out, T);
}